// Round 3
// baseline (124.622 us; speedup 1.0000x reference)
//
#include <hip/hip_runtime.h>
#include <hip/hip_bf16.h>

#define DN   256     // feature dim D
#define KC   128     // mixture components K
#define NTOT 8192    // rows N

typedef __attribute__((ext_vector_type(4)))  float f32x4;
typedef __attribute__((ext_vector_type(16))) float f32x16;
typedef __attribute__((ext_vector_type(4)))  unsigned int u32x4;
typedef __attribute__((ext_vector_type(8)))  int i32x8;

// pack 4 f32 -> 4 fp8 e4m3 (OCP, RNE+sat) in one u32, bytes ascending
__device__ __forceinline__ unsigned pk4(float a0, float a1, float a2, float a3) {
  int v = __builtin_amdgcn_cvt_pk_fp8_f32(a0, a1, 0, false);
  v = __builtin_amdgcn_cvt_pk_fp8_f32(a2, a3, v, true);
  return (unsigned)v;
}
// f32 -> e4m3 -> f32 round trip (for consistent C vector)
__device__ __forceinline__ float rt8(float v) {
  int p = __builtin_amdgcn_cvt_pk_fp8_f32(v, v, 0, false);
  return __builtin_amdgcn_cvt_f32_fp8(p, 0);
}

__device__ __forceinline__ void gload16(const void* g, void* l) {
  __builtin_amdgcn_global_load_lds(
      (const __attribute__((address_space(1))) unsigned int*)g,
      (__attribute__((address_space(3))) unsigned int*)l, 16, 0, 0);
}

// LDS granule map (rows x 64-byte rows, granule = 16B, 4 per row):
// row r, granule g(0..3): line l2 = r>>1, slot = (g + 4*(r&1)) ^ (l2&7),
// LDS granule index gi = l2*8 + slot.  Inverse:
__device__ __forceinline__ void inv_gran(int gi, int& r, int& g) {
  int l2 = gi >> 3, slot = gi & 7;
  int ss = slot ^ (l2 & 7);
  r = 2 * l2 + (ss >> 2);
  g = ss & 3;
}

// ---------------------------------------------------------------------------
// Fused prep kernel (replaces gmm_const + gmm_cvec + gmm_packA + gmm_packB;
// each branch is a verbatim port of the round-0 proven kernel).
// Blocks [0,2048): pack M (masked tril+diag -> fp8) AND accumulate
// C[k,d] = sum_e fp8(M)*mean via atomicAdd (C pre-zeroed by memset; skips
// the tri load for all-zero strictly-upper granules). Blocks [2048,2560):
// pack X. Blocks [2560,2592): ck[k] = sum log|diag| + log_softmax(weigh).
// ---------------------------------------------------------------------------
__global__ __launch_bounds__(256) void gmm_prep(
    const float* __restrict__ x, const float* __restrict__ tri,
    const float* __restrict__ diag, const float* __restrict__ means,
    const float* __restrict__ weigh,
    unsigned char* __restrict__ Xp, unsigned char* __restrict__ Mp,
    float* __restrict__ C, float* __restrict__ ck) {
  int b = blockIdx.x;
  if (b < 2048) {
    // --- pack M + fused C accumulation ---
    int t = b * 256 + (int)threadIdx.x;  // < 524288
    int k = t >> 12;
    int rem = t & 4095;
    int tc = rem >> 10;
    int r2 = rem & 1023;
    int dhh = r2 >> 9;
    int gi = r2 & 511;
    int r, g; inv_gran(gi, r, g);
    int d = dhh * 128 + r;
    int e0 = tc * 64 + g * 16;
    if (e0 > d) {
      // entirely strictly-upper: zeros, no tri read, no C contribution
      u32x4 o = {0u, 0u, 0u, 0u};
      *(u32x4*)(Mp + (size_t)t * 16) = o;
    } else {
      const float* src = tri + (((size_t)k) << 16) + (d << 8) + e0;
      float dg = diag[(k << 8) + d];
      float4 v0 = *(const float4*)src;
      float4 v1 = *(const float4*)(src + 4);
      float4 v2 = *(const float4*)(src + 8);
      float4 v3 = *(const float4*)(src + 12);
      float f[16] = {v0.x, v0.y, v0.z, v0.w, v1.x, v1.y, v1.z, v1.w,
                     v2.x, v2.y, v2.z, v2.w, v3.x, v3.y, v3.z, v3.w};
#pragma unroll
      for (int jj = 0; jj < 16; ++jj) {
        int e = e0 + jj;
        f[jj] = (e < d) ? f[jj] : ((e == d) ? dg : 0.f);
      }
      u32x4 o = {pk4(f[0], f[1], f[2], f[3]), pk4(f[4], f[5], f[6], f[7]),
                 pk4(f[8], f[9], f[10], f[11]), pk4(f[12], f[13], f[14], f[15])};
      *(u32x4*)(Mp + (size_t)t * 16) = o;
      // C partial from the fp8 bytes themselves (matches gemm exactly)
      float part = 0.f;
      const float* mrow = means + (k << 8) + e0;
#pragma unroll
      for (int w = 0; w < 4; ++w) {
        float4 mv = *(const float4*)(mrow + 4 * w);
        part += __builtin_amdgcn_cvt_f32_fp8((int)o[w], 0) * mv.x;
        part += __builtin_amdgcn_cvt_f32_fp8((int)o[w], 1) * mv.y;
        part += __builtin_amdgcn_cvt_f32_fp8((int)o[w], 2) * mv.z;
        part += __builtin_amdgcn_cvt_f32_fp8((int)o[w], 3) * mv.w;
      }
      atomicAdd(&C[(k << 8) + d], part);
    }
  } else if (b < 2560) {
    // --- pack X ---
    int t = (b - 2048) * 256 + (int)threadIdx.x;  // < 131072
    int rb = t >> 12;
    int rem = t & 4095;
    int tc = rem >> 10;
    int gi = rem & 1023;
    int r, g; inv_gran(gi, r, g);
    int row = rb * 256 + r;
    int e0 = tc * 64 + g * 16;
    const float* src = x + (size_t)row * DN + e0;
    float4 v0 = *(const float4*)src;
    float4 v1 = *(const float4*)(src + 4);
    float4 v2 = *(const float4*)(src + 8);
    float4 v3 = *(const float4*)(src + 12);
    u32x4 o = {pk4(v0.x, v0.y, v0.z, v0.w), pk4(v1.x, v1.y, v1.z, v1.w),
               pk4(v2.x, v2.y, v2.z, v2.w), pk4(v3.x, v3.y, v3.z, v3.w)};
    *(u32x4*)(Xp + (size_t)t * 16) = o;
  } else {
    // --- ck: 4 components per block (one per wave) ---
    int lane = (int)threadIdx.x & 63;
    int kk = (b - 2560) * 4 + ((int)threadIdx.x >> 6);
    float w0 = weigh[lane], w1 = weigh[64 + lane];
    float mx = fmaxf(w0, w1);
#pragma unroll
    for (int off = 32; off > 0; off >>= 1) mx = fmaxf(mx, __shfl_xor(mx, off, 64));
    float s = expf(w0 - mx) + expf(w1 - mx);
#pragma unroll
    for (int off = 32; off > 0; off >>= 1) s += __shfl_xor(s, off, 64);
    float lse = mx + logf(s);
    float ld = 0.f;
    const float* dp = diag + (size_t)kk * DN;
#pragma unroll
    for (int jj = 0; jj < 4; ++jj) ld += logf(fabsf(dp[lane + 64 * jj]));
#pragma unroll
    for (int off = 32; off > 0; off >>= 1) ld += __shfl_xor(ld, off, 64);
    if (lane == 0) ck[kk] = ld + weigh[kk] - lse;
  }
}

// ---------------------------------------------------------------------------
// Main fused GEMM — MX-fp8 32x32x64 (scales=1.0), d-split, tri-skip.
// VERBATIM round-0 proven kernel (116.6us run).
// Block = (k, rb 256 n-rows, dh 128-d half). Chunks of K=64 e; NT = 2+2*dh.
// A = M-tile [128 d][64 e] fp8; B = X-tile [256 n][64 e] fp8. 8 waves =
// 4 n-groups x 2 d-groups; wave frags: d = dh*128 + df*64 + wn*32 (df 0..1,
// interleaved for balance; frag active iff 2*dh+df >= t), n = wm*64 + nf*32.
// C/D: col = n = lane&31, row(d) = (q&3)+8*(q>>2)+4*(lane>>5) -> s-reduce is
// one shfl_xor(32). Ring-3 LDS, depth-2 prefetch, counted vmcnt(6/3/0).
// ---------------------------------------------------------------------------
template <int USEP>
__global__ __launch_bounds__(512, 4) void gmm_gemm(
    const float* __restrict__ x, const float* __restrict__ tri,
    const float* __restrict__ diag, const unsigned char* __restrict__ Xp,
    const unsigned char* __restrict__ Mp, const float* __restrict__ C,
    float* __restrict__ Sp) {
  __shared__ __attribute__((aligned(16))) unsigned char As[3][8192];   // M
  __shared__ __attribute__((aligned(16))) unsigned char Bs[3][16384];  // X
  __shared__ float C_lds[128];
  __shared__ float spart[256][2];   // 74.5 KB total -> 2 blocks/CU

  const int tid  = threadIdx.x;
  const int lane = tid & 63;
  const int wid  = tid >> 6;
  const int wm   = wid >> 1;    // 0..3: 64-n group
  const int wn   = wid & 1;     // 0..1: d interleave phase
  const int l31  = lane & 31;
  const int h    = lane >> 5;

  // XCD-aware bijective swizzle: XCD x owns k in [16x,16x+16).
  const int bid = blockIdx.x;          // 0..8191
  const int xcd = bid & 7;
  const int j   = bid >> 3;
  const int k   = xcd * 16 + (j & 15);
  const int u   = j >> 4;              // 0..63
  const int dh  = u & 1;
  const int rb  = u >> 1;              // 0..31
  const int NT  = 2 + 2 * dh;

  f32x16 acc[2][2];
#pragma unroll
  for (int df = 0; df < 2; ++df)
#pragma unroll
    for (int nf = 0; nf < 2; ++nf)
#pragma unroll
      for (int q = 0; q < 16; ++q) acc[df][nf][q] = 0.f;

  // per-lane swizzled read offsets (bytes). A row: wn*32+l31 (+df*4096),
  // B row: wm*64+l31 (+nf*2048). granules g = 2h, 2h+1.
  const int rA = wn * 32 + l31, lA = rA >> 1;
  const int rB = wm * 64 + l31, lB = rB >> 1;
  const int aoff0 = lA * 128 + (((2 * h)     + 4 * (rA & 1)) ^ (lA & 7)) * 16;
  const int aoff1 = lA * 128 + (((2 * h + 1) + 4 * (rA & 1)) ^ (lA & 7)) * 16;
  const int boff0 = lB * 128 + (((2 * h)     + 4 * (rB & 1)) ^ (lB & 7)) * 16;
  const int boff1 = lB * 128 + (((2 * h + 1) + 4 * (rB & 1)) ^ (lB & 7)) * 16;

  auto stage = [&](int ring, int tc) {
    // A(M): 512 granules, 1/thread ; B(X): 1024 granules, 2/thread
    gload16(Mp + (((size_t)((k * 4 + tc) * 2 + dh)) * 512 + tid) * 16,
            &As[ring][wid * 1024]);
    const unsigned char* gb = Xp + (((size_t)(rb * 4 + tc)) * 1024 + tid) * 16;
    gload16(gb, &Bs[ring][wid * 1024]);
    gload16(gb + 512 * 16, &Bs[ring][8192 + wid * 1024]);
  };

  auto compute = [&](int ring, int t) {
    const char* Ab = (const char*)&As[ring][0];
    const char* Bb = (const char*)&Bs[ring][0];
    u32x4 xlo[2], xhi[2];
#pragma unroll
    for (int nf = 0; nf < 2; ++nf) {
      xlo[nf] = *(const u32x4*)(Bb + boff0 + nf * 2048);
      xhi[nf] = *(const u32x4*)(Bb + boff1 + nf * 2048);
    }
#pragma unroll
    for (int df = 0; df < 2; ++df) {
      if (2 * dh + df >= t) {   // tril skip (wave-uniform)
        u32x4 m0 = *(const u32x4*)(Ab + aoff0 + df * 4096);
        u32x4 m1 = *(const u32x4*)(Ab + aoff1 + df * 4096);
        i32x8 ma;
#pragma unroll
        for (int q = 0; q < 4; ++q) { ma[q] = (int)m0[q]; ma[4 + q] = (int)m1[q]; }
#pragma unroll
        for (int nf = 0; nf < 2; ++nf) {
          i32x8 xb;
#pragma unroll
          for (int q = 0; q < 4; ++q) { xb[q] = (int)xlo[nf][q]; xb[4 + q] = (int)xhi[nf][q]; }
          acc[df][nf] = __builtin_amdgcn_mfma_scale_f32_32x32x64_f8f6f4(
              ma, xb, acc[df][nf], 0, 0, 0, 0x7f7f7f7f, 0, 0x7f7f7f7f);
        }
      }
    }
  };

  // prologue: C vector into LDS (drained by syncthreads before any prefetch)
  if (tid < 128) C_lds[tid] = C[(k << 8) + dh * 128 + tid];
  __syncthreads();

  if (USEP) {
    stage(0, 0); stage(1, 1);   // depth-2 prefetch, 6 vmem/thread
    int rc = 0;
    for (int t = 0; t < NT; ++t) {
      if (t + 2 < NT) { int rs = rc + 2; if (rs >= 3) rs -= 3; stage(rs, t + 2); }
      int infl = NT - 1 - t; if (infl > 2) infl = 2;
      if (infl == 2)      asm volatile("s_waitcnt vmcnt(6)" ::: "memory");
      else if (infl == 1) asm volatile("s_waitcnt vmcnt(3)" ::: "memory");
      else                asm volatile("s_waitcnt vmcnt(0)" ::: "memory");
      __builtin_amdgcn_s_barrier();
      __builtin_amdgcn_sched_barrier(0);
      compute(rc, t);
      __builtin_amdgcn_s_barrier();
      __builtin_amdgcn_sched_barrier(0);
      if (++rc == 3) rc = 0;
    }
  } else {
    // fallback: on-the-fly fp32->fp8 staging via ds_write
    int rc = 0;
    for (int t = 0; t < NT; ++t) {
      __syncthreads();
      {
        int r, g; inv_gran(tid & 511, r, g);
        if (tid < 512) {
          int d = dh * 128 + r;
          int e0 = t * 64 + g * 16;
          const float* st = tri + (((size_t)k) << 16) + (d << 8) + e0;
          float dg = diag[(k << 8) + d];
          float f[16];
#pragma unroll
          for (int jj = 0; jj < 16; ++jj) {
            int e = e0 + jj;
            f[jj] = (e < d) ? st[jj] : ((e == d) ? dg : 0.f);
          }
          u32x4 o = {pk4(f[0], f[1], f[2], f[3]), pk4(f[4], f[5], f[6], f[7]),
                     pk4(f[8], f[9], f[10], f[11]), pk4(f[12], f[13], f[14], f[15])};
          *(u32x4*)&As[rc][(tid & 511) * 16] = o;
        }
      }
#pragma unroll
      for (int i = 0; i < 2; ++i) {
        int gi = i * 512 + tid;
        int r, g; inv_gran(gi, r, g);
        int row = rb * 256 + r;
        int e0 = t * 64 + g * 16;
        const float* sx = x + ((size_t)row << 8) + e0;
        float4 v0 = *(const float4*)sx;
        float4 v1 = *(const float4*)(sx + 4);
        float4 v2 = *(const float4*)(sx + 8);
        float4 v3 = *(const float4*)(sx + 12);
        u32x4 o = {pk4(v0.x, v0.y, v0.z, v0.w), pk4(v1.x, v1.y, v1.z, v1.w),
                   pk4(v2.x, v2.y, v2.z, v2.w), pk4(v3.x, v3.y, v3.z, v3.w)};
        *(u32x4*)&Bs[rc][gi * 16] = o;
      }
      __syncthreads();
      compute(rc, t);
      if (++rc == 3) rc = 0;
    }
    __syncthreads();
  }

  // ---- epilogue: subtract C, square, reduce ----
  // z(d,n): d = dh*128 + df*64 + wn*32 + (q&3)+8*(q>>2)+4*h ; n = wm*64+nf*32+l31
  float s0 = 0.f, s1 = 0.f;
#pragma unroll
  for (int df = 0; df < 2; ++df)
#pragma unroll
    for (int qg = 0; qg < 4; ++qg) {
      f32x4 cv = *(const f32x4*)&C_lds[df * 64 + wn * 32 + qg * 8 + 4 * h];
#pragma unroll
      for (int qi = 0; qi < 4; ++qi) {
        int q = qg * 4 + qi;
        float z0 = acc[df][0][q] - cv[qi];
        float z1 = acc[df][1][q] - cv[qi];
        s0 += z0 * z0;
        s1 += z1 * z1;
      }
    }
  s0 += __shfl_xor(s0, 32, 64);
  s1 += __shfl_xor(s1, 32, 64);
  if (lane < 32) {
    spart[wm * 64 + l31][wn]      = s0;
    spart[wm * 64 + 32 + l31][wn] = s1;
  }
  __syncthreads();
  if (tid < 256)
    Sp[((size_t)(dh * KC + k)) * NTOT + rb * 256 + tid] =
        spart[tid][0] + spart[tid][1];
}

// ---------------------------------------------------------------------------
// Per-row logsumexp over K (combining d-half partials), mean(|logC+lse|).
// VERBATIM round-0.
// ---------------------------------------------------------------------------
__global__ void gmm_lse(const float* __restrict__ Sp,
                        const float* __restrict__ ck,
                        float* __restrict__ out) {
  int n = blockIdx.x * 256 + threadIdx.x;
  float m = -1e30f, s = 0.f;
#pragma unroll 4
  for (int kk = 0; kk < KC; ++kk) {
    float sv = Sp[(size_t)kk * NTOT + n] + Sp[(size_t)(KC + kk) * NTOT + n];
    float v = ck[kk] - 0.5f * sv;
    float nm = fmaxf(m, v);
    s = s * expf(m - nm) + expf(v - nm);
    m = nm;
  }
  float lse = m + logf(s);
  const float logC = -(DN * 0.5f) * 1.8378770664093453f;  // -(D/2) log(2*pi)
  float val = fabsf(logC + lse) * (1.0f / (float)NTOT);
  int lane = threadIdx.x & 63;
  int wid  = threadIdx.x >> 6;
#pragma unroll
  for (int off = 32; off > 0; off >>= 1) val += __shfl_down(val, off, 64);
  __shared__ float wsum[4];
  if (lane == 0) wsum[wid] = val;
  __syncthreads();
  if (threadIdx.x == 0)
    atomicAdd(out, wsum[0] + wsum[1] + wsum[2] + wsum[3]);
}

// ---------------------------------------------------------------------------
// Fallback-path side kernels (verbatim round-0; used when workspace small).
// ---------------------------------------------------------------------------
__global__ void gmm_const(const float* __restrict__ diag,
                          const float* __restrict__ weigh,
                          float* __restrict__ ck) {
  int k = blockIdx.x;
  int lane = threadIdx.x;
  float w0 = weigh[lane], w1 = weigh[64 + lane];
  float mx = fmaxf(w0, w1);
#pragma unroll
  for (int off = 32; off > 0; off >>= 1) mx = fmaxf(mx, __shfl_xor(mx, off, 64));
  float s = expf(w0 - mx) + expf(w1 - mx);
#pragma unroll
  for (int off = 32; off > 0; off >>= 1) s += __shfl_xor(s, off, 64);
  float lse = mx + logf(s);
  float ld = 0.f;
  const float* dp = diag + (size_t)k * DN;
#pragma unroll
  for (int j = 0; j < 4; ++j) ld += logf(fabsf(dp[lane + 64 * j]));
#pragma unroll
  for (int off = 32; off > 0; off >>= 1) ld += __shfl_xor(ld, off, 64);
  if (lane == 0) ck[k] = ld + weigh[k] - lse;
}

__global__ void gmm_cvec(const float* __restrict__ tri,
                         const float* __restrict__ diag,
                         const float* __restrict__ means,
                         float* __restrict__ C) {
  int k  = blockIdx.x >> 2;
  int d0 = (blockIdx.x & 3) * 64;
  int lane = threadIdx.x & 63;
  int wid  = threadIdx.x >> 6;
  for (int i = 0; i < 16; ++i) {
    int d = d0 + wid * 16 + i;
    const float* trow = tri + (((size_t)k) << 16) + (d << 8);
    float dg = diag[(k << 8) + d];
    float acc = 0.f;
#pragma unroll
    for (int eb = 0; eb < DN; eb += 64) {
      int e = eb + lane;
      float mv = (e < d) ? trow[e] : ((e == d) ? dg : 0.f);
      acc += rt8(mv) * means[(k << 8) + e];
    }
#pragma unroll
    for (int off = 32; off > 0; off >>= 1) acc += __shfl_xor(acc, off, 64);
    if (lane == 0) C[(k << 8) + d] = acc;
  }
}

// ---------------------------------------------------------------------------
extern "C" void kernel_launch(void* const* d_in, const int* in_sizes, int n_in,
                              void* d_out, int out_size, void* d_ws, size_t ws_size,
                              hipStream_t stream) {
  const float* x     = (const float*)d_in[0];
  const float* means = (const float*)d_in[1];
  const float* diag  = (const float*)d_in[2];
  const float* tri   = (const float*)d_in[3];
  const float* weigh = (const float*)d_in[4];
  float* out = (float*)d_out;

  char* ws = (char*)d_ws;
  size_t off_ck = 0;                                    // 1 KB
  size_t off_C  = 1024;                                 // 128 KB
  size_t off_Sp = off_C + (size_t)KC * DN * 4;          // 8 MB (2 halves)
  size_t off_Xp = off_Sp + (size_t)2 * KC * NTOT * 4;   // 2 MB (fp8)
  size_t off_Mp = off_Xp + (size_t)NTOT * DN;           // 8 MB (fp8)
  size_t need   = off_Mp + (size_t)KC * DN * DN;        // ~18.6 MB
  int useP = (ws_size >= need) ? 1 : 0;

  float* ck = (float*)(ws + off_ck);
  float* C  = (float*)(ws + off_C);
  float* Sp = (float*)(ws + off_Sp);
  unsigned char* Xp = (unsigned char*)(ws + off_Xp);
  unsigned char* Mp = (unsigned char*)(ws + off_Mp);

  hipMemsetAsync(d_out, 0, sizeof(float), stream);
  if (useP) {
    hipMemsetAsync(C, 0, (size_t)KC * DN * 4, stream);
    gmm_prep<<<2592, 256, 0, stream>>>(x, tri, diag, means, weigh, Xp, Mp, C, ck);
    gmm_gemm<1><<<8192, 512, 0, stream>>>(x, tri, diag, Xp, Mp, C, Sp);
  } else {
    gmm_const<<<KC, 64, 0, stream>>>(diag, weigh, ck);
    gmm_cvec<<<KC * 4, 256, 0, stream>>>(tri, diag, means, C);
    gmm_gemm<0><<<8192, 512, 0, stream>>>(x, tri, diag, Xp, Mp, C, Sp);
  }
  gmm_lse<<<NTOT / 256, 256, 0, stream>>>(Sp, ck, out);
}

// Round 4
// 122.040 us; speedup vs baseline: 1.0212x; 1.0212x over previous
//
#include <hip/hip_runtime.h>
#include <hip/hip_bf16.h>

#define DN   256     // feature dim D
#define KC   128     // mixture components K
#define NTOT 8192    // rows N

typedef __attribute__((ext_vector_type(4)))  float f32x4;
typedef __attribute__((ext_vector_type(16))) float f32x16;
typedef __attribute__((ext_vector_type(4)))  unsigned int u32x4;
typedef __attribute__((ext_vector_type(8)))  int i32x8;

// pack 4 f32 -> 4 fp8 e4m3 (OCP, RNE+sat) in one u32, bytes ascending
__device__ __forceinline__ unsigned pk4(float a0, float a1, float a2, float a3) {
  int v = __builtin_amdgcn_cvt_pk_fp8_f32(a0, a1, 0, false);
  v = __builtin_amdgcn_cvt_pk_fp8_f32(a2, a3, v, true);
  return (unsigned)v;
}
// f32 -> e4m3 -> f32 round trip (for consistent C vector)
__device__ __forceinline__ float rt8(float v) {
  int p = __builtin_amdgcn_cvt_pk_fp8_f32(v, v, 0, false);
  return __builtin_amdgcn_cvt_f32_fp8(p, 0);
}

__device__ __forceinline__ void gload16(const void* g, void* l) {
  __builtin_amdgcn_global_load_lds(
      (const __attribute__((address_space(1))) unsigned int*)g,
      (__attribute__((address_space(3))) unsigned int*)l, 16, 0, 0);
}

// LDS granule map (rows x 64-byte rows, granule = 16B, 4 per row):
// row r, granule g(0..3): line l2 = r>>1, slot = (g + 4*(r&1)) ^ (l2&7),
// LDS granule index gi = l2*8 + slot.  Inverse:
__device__ __forceinline__ void inv_gran(int gi, int& r, int& g) {
  int l2 = gi >> 3, slot = gi & 7;
  int ss = slot ^ (l2 & 7);
  r = 2 * l2 + (ss >> 2);
  g = ss & 3;
}

// ---------------------------------------------------------------------------
// ck[k] = sum_d log|diag[k,d]| + log_softmax(weigh)[k].  128 blocks x 64 thr.
// (verbatim round-0)
// ---------------------------------------------------------------------------
__global__ void gmm_const(const float* __restrict__ diag,
                          const float* __restrict__ weigh,
                          float* __restrict__ ck) {
  int k = blockIdx.x;
  int lane = threadIdx.x;
  float w0 = weigh[lane], w1 = weigh[64 + lane];
  float mx = fmaxf(w0, w1);
#pragma unroll
  for (int off = 32; off > 0; off >>= 1) mx = fmaxf(mx, __shfl_xor(mx, off, 64));
  float s = expf(w0 - mx) + expf(w1 - mx);
#pragma unroll
  for (int off = 32; off > 0; off >>= 1) s += __shfl_xor(s, off, 64);
  float lse = mx + logf(s);
  float ld = 0.f;
  const float* dp = diag + (size_t)k * DN;
#pragma unroll
  for (int j = 0; j < 4; ++j) ld += logf(fabsf(dp[lane + 64 * j]));
#pragma unroll
  for (int off = 32; off > 0; off >>= 1) ld += __shfl_xor(ld, off, 64);
  if (lane == 0) ck[k] = ld + weigh[k] - lse;
}

// ---------------------------------------------------------------------------
// C[k,d] = sum_e fp8(M[k,d,e]) * mean[k,e], f32 acc.  512 blocks x 256 thr.
// (verbatim round-0)
// ---------------------------------------------------------------------------
__global__ void gmm_cvec(const float* __restrict__ tri,
                         const float* __restrict__ diag,
                         const float* __restrict__ means,
                         float* __restrict__ C) {
  int k  = blockIdx.x >> 2;
  int d0 = (blockIdx.x & 3) * 64;
  int lane = threadIdx.x & 63;
  int wid  = threadIdx.x >> 6;
  for (int i = 0; i < 16; ++i) {
    int d = d0 + wid * 16 + i;
    const float* trow = tri + (((size_t)k) << 16) + (d << 8);
    float dg = diag[(k << 8) + d];
    float acc = 0.f;
#pragma unroll
    for (int eb = 0; eb < DN; eb += 64) {
      int e = eb + lane;
      float mv = (e < d) ? trow[e] : ((e == d) ? dg : 0.f);
      acc += rt8(mv) * means[(k << 8) + e];
    }
#pragma unroll
    for (int off = 32; off > 0; off >>= 1) acc += __shfl_xor(acc, off, 64);
    if (lane == 0) C[(k << 8) + d] = acc;
  }
}

// ---------------------------------------------------------------------------
// Pack X (B operand): Xp granule t = (rb*4 + tc)*1024 + gi, gi ~ [256 rows][4g]
// swizzled; pre-inverse-swizzled so linear global_load_lds lands swizzled.
// (verbatim round-0)
// ---------------------------------------------------------------------------
__global__ void gmm_packA(const float* __restrict__ x,
                          unsigned char* __restrict__ Xp) {
  int t = blockIdx.x * 256 + threadIdx.x;  // < 32*4*1024 = 131072
  int rb = t >> 12;
  int rem = t & 4095;
  int tc = rem >> 10;
  int gi = rem & 1023;
  int r, g; inv_gran(gi, r, g);
  int row = rb * 256 + r;
  int e0 = tc * 64 + g * 16;
  const float* src = x + (size_t)row * DN + e0;
  float4 v0 = *(const float4*)src;
  float4 v1 = *(const float4*)(src + 4);
  float4 v2 = *(const float4*)(src + 8);
  float4 v3 = *(const float4*)(src + 12);
  u32x4 o = {pk4(v0.x, v0.y, v0.z, v0.w), pk4(v1.x, v1.y, v1.z, v1.w),
             pk4(v2.x, v2.y, v2.z, v2.w), pk4(v3.x, v3.y, v3.z, v3.w)};
  *(u32x4*)(Xp + (size_t)t * 16) = o;
}

// ---------------------------------------------------------------------------
// Pack M (A operand): Mp granule t = ((k*4+tc)*2+dh)*512 + gi, gi ~ [128 d
// rows][4 g] swizzled; masked tril + diag, fp8.  Round-0 + the r3-certified
// all-zero skip for strictly-upper granules (no tri load).
// ---------------------------------------------------------------------------
__global__ void gmm_packB(const float* __restrict__ tri,
                          const float* __restrict__ diag,
                          unsigned char* __restrict__ Mp) {
  int t = blockIdx.x * 256 + threadIdx.x;  // < 128*4*2*512 = 524288
  int k = t >> 12;
  int rem = t & 4095;
  int tc = rem >> 10;
  int r2 = rem & 1023;
  int dhh = r2 >> 9;
  int gi = r2 & 511;
  int r, g; inv_gran(gi, r, g);
  int d = dhh * 128 + r;
  int e0 = tc * 64 + g * 16;
  if (e0 > d) {
    u32x4 o = {0u, 0u, 0u, 0u};
    *(u32x4*)(Mp + (size_t)t * 16) = o;
    return;
  }
  const float* src = tri + (((size_t)k) << 16) + (d << 8) + e0;
  float dg = diag[(k << 8) + d];
  float4 v0 = *(const float4*)src;
  float4 v1 = *(const float4*)(src + 4);
  float4 v2 = *(const float4*)(src + 8);
  float4 v3 = *(const float4*)(src + 12);
  float f[16] = {v0.x, v0.y, v0.z, v0.w, v1.x, v1.y, v1.z, v1.w,
                 v2.x, v2.y, v2.z, v2.w, v3.x, v3.y, v3.z, v3.w};
#pragma unroll
  for (int j = 0; j < 16; ++j) {
    int e = e0 + j;
    f[j] = (e < d) ? f[j] : ((e == d) ? dg : 0.f);
  }
  u32x4 o = {pk4(f[0], f[1], f[2], f[3]), pk4(f[4], f[5], f[6], f[7]),
             pk4(f[8], f[9], f[10], f[11]), pk4(f[12], f[13], f[14], f[15])};
  *(u32x4*)(Mp + (size_t)t * 16) = o;
}

// ---------------------------------------------------------------------------
// Main fused GEMM — MX-fp8 32x32x64 (scales=1.0).  NEW geometry on the
// round-0 proven control skeleton.  One block = FULL 256d x 256n for one
// (k, rb): 4096 blocks, uniform NT=4.  8 waves = 4 n-groups (wm) x 2 frag
// parities (ws).  Wave (wm,ws): n = wm*64 + nf*32, d-frags fi: d = ws*32 +
// fi*64 (+ intra-frag rows).  acc[4][2] f32x16 (128 f32/lane).  Tril-skip:
// frag fi active at e-chunk t iff fi >= t (both parities identical ->
// perfectly balanced 4+3+2+1 schedule).  A-frag fi at LDS byte aoff+fi*4096
// (64-row step = 32 lines = 0 mod 8 keeps the XOR swizzle invariant; byte
// map is linear across the 16KB buffer).  Ring-3 LDS, depth-2 prefetch,
// counted vmcnt(8/4/0) (4 loads/stage).  Epilogue: subtract C, square,
// reduce; 2-plane Sp (parity partials) into the proven lse.
// ---------------------------------------------------------------------------
template <int USEP>
__global__ __launch_bounds__(512, 2) void gmm_gemm(
    const float* __restrict__ x, const float* __restrict__ tri,
    const float* __restrict__ diag, const unsigned char* __restrict__ Xp,
    const unsigned char* __restrict__ Mp, const float* __restrict__ C,
    float* __restrict__ Sp) {
  __shared__ __attribute__((aligned(16))) unsigned char As[3][16384];  // M 256dx64e
  __shared__ __attribute__((aligned(16))) unsigned char Bs[3][16384];  // X 256nx64e
  __shared__ float C_lds[256];
  __shared__ float spart[256][2];   // 99.25 KB total -> 1 block/CU

  const int tid  = threadIdx.x;
  const int lane = tid & 63;
  const int wid  = tid >> 6;
  const int wm   = wid >> 1;    // 0..3: 64-n group
  const int ws   = wid & 1;     // frag parity
  const int l31  = lane & 31;
  const int h    = lane >> 5;

  // XCD-aware bijective swizzle: XCD x owns k in [16x,16x+16).
  const int bid = blockIdx.x;          // 0..4095
  const int xcd = bid & 7;
  const int j   = bid >> 3;
  const int k   = xcd * 16 + (j & 15);
  const int rb  = j >> 4;              // 0..31
  const int NT  = 4;

  f32x16 acc[4][2];
#pragma unroll
  for (int fi = 0; fi < 4; ++fi)
#pragma unroll
    for (int nf = 0; nf < 2; ++nf)
#pragma unroll
      for (int q = 0; q < 16; ++q) acc[fi][nf][q] = 0.f;

  // per-lane swizzled read offsets (bytes). A row: ws*32+l31 (+fi*4096),
  // B row: wm*64+l31 (+nf*2048). granules g = 2h, 2h+1.
  const int rA = ws * 32 + l31, lA = rA >> 1;
  const int rB = wm * 64 + l31, lB = rB >> 1;
  const int aoff0 = lA * 128 + (((2 * h)     + 4 * (rA & 1)) ^ (lA & 7)) * 16;
  const int aoff1 = lA * 128 + (((2 * h + 1) + 4 * (rA & 1)) ^ (lA & 7)) * 16;
  const int boff0 = lB * 128 + (((2 * h)     + 4 * (rB & 1)) ^ (lB & 7)) * 16;
  const int boff1 = lB * 128 + (((2 * h + 1) + 4 * (rB & 1)) ^ (lB & 7)) * 16;

  auto stage = [&](int ring, int tc) {
    // A(M): 1024 granules (both d-halves of chunk (k,tc) contiguous in Mp),
    // 2/thread; B(X): 1024 granules, 2/thread.  4 global_load_lds/thread.
    const unsigned char* ga = Mp + (((size_t)(k * 4 + tc)) * 1024 + tid) * 16;
    gload16(ga, &As[ring][wid * 1024]);
    gload16(ga + 8192, &As[ring][8192 + wid * 1024]);
    const unsigned char* gb = Xp + (((size_t)(rb * 4 + tc)) * 1024 + tid) * 16;
    gload16(gb, &Bs[ring][wid * 1024]);
    gload16(gb + 8192, &Bs[ring][8192 + wid * 1024]);
  };

  auto compute = [&](int ring, int t) {
    const char* Ab = (const char*)&As[ring][0];
    const char* Bb = (const char*)&Bs[ring][0];
    u32x4 xlo[2], xhi[2];
#pragma unroll
    for (int nf = 0; nf < 2; ++nf) {
      xlo[nf] = *(const u32x4*)(Bb + boff0 + nf * 2048);
      xhi[nf] = *(const u32x4*)(Bb + boff1 + nf * 2048);
    }
#pragma unroll
    for (int fi = 0; fi < 4; ++fi) {
      if (fi >= t) {   // tril skip (wave-uniform)
        u32x4 m0 = *(const u32x4*)(Ab + aoff0 + fi * 4096);
        u32x4 m1 = *(const u32x4*)(Ab + aoff1 + fi * 4096);
        i32x8 ma;
#pragma unroll
        for (int q = 0; q < 4; ++q) { ma[q] = (int)m0[q]; ma[4 + q] = (int)m1[q]; }
#pragma unroll
        for (int nf = 0; nf < 2; ++nf) {
          i32x8 xb;
#pragma unroll
          for (int q = 0; q < 4; ++q) { xb[q] = (int)xlo[nf][q]; xb[4 + q] = (int)xhi[nf][q]; }
          acc[fi][nf] = __builtin_amdgcn_mfma_scale_f32_32x32x64_f8f6f4(
              ma, xb, acc[fi][nf], 0, 0, 0, 0x7f7f7f7f, 0, 0x7f7f7f7f);
        }
      }
    }
  };

  // prologue: C vector into LDS (drained by syncthreads before any prefetch)
  if (tid < 256) C_lds[tid] = C[(k << 8) + tid];
  __syncthreads();

  if (USEP) {
    stage(0, 0); stage(1, 1);   // depth-2 prefetch, 8 vmem/thread
    int rc = 0;
    for (int t = 0; t < NT; ++t) {
      if (t + 2 < NT) { int rs = rc + 2; if (rs >= 3) rs -= 3; stage(rs, t + 2); }
      int infl = NT - 1 - t; if (infl > 2) infl = 2;
      if (infl == 2)      asm volatile("s_waitcnt vmcnt(8)" ::: "memory");
      else if (infl == 1) asm volatile("s_waitcnt vmcnt(4)" ::: "memory");
      else                asm volatile("s_waitcnt vmcnt(0)" ::: "memory");
      __builtin_amdgcn_s_barrier();
      __builtin_amdgcn_sched_barrier(0);
      compute(rc, t);
      __builtin_amdgcn_s_barrier();
      __builtin_amdgcn_sched_barrier(0);
      if (++rc == 3) rc = 0;
    }
  } else {
    // fallback: on-the-fly fp32->fp8 staging via ds_write
    int rc = 0;
    for (int t = 0; t < NT; ++t) {
      __syncthreads();
#pragma unroll
      for (int i = 0; i < 2; ++i) {   // A: both d-halves
        int gi = i * 512 + tid;       // LDS granule == Mp granule order
        int half = gi >> 9;
        int r, g; inv_gran(gi & 511, r, g);
        int d = half * 128 + r;
        int e0 = t * 64 + g * 16;
        float f[16];
        if (e0 > d) {
#pragma unroll
          for (int jj = 0; jj < 16; ++jj) f[jj] = 0.f;
        } else {
          const float* st = tri + (((size_t)k) << 16) + (d << 8) + e0;
          float dg = diag[(k << 8) + d];
#pragma unroll
          for (int jj = 0; jj < 16; ++jj) {
            int e = e0 + jj;
            f[jj] = (e < d) ? st[jj] : ((e == d) ? dg : 0.f);
          }
        }
        u32x4 o = {pk4(f[0], f[1], f[2], f[3]), pk4(f[4], f[5], f[6], f[7]),
                   pk4(f[8], f[9], f[10], f[11]), pk4(f[12], f[13], f[14], f[15])};
        *(u32x4*)&As[rc][gi * 16] = o;
      }
#pragma unroll
      for (int i = 0; i < 2; ++i) {   // B
        int gi = i * 512 + tid;
        int r, g; inv_gran(gi, r, g);
        int row = rb * 256 + r;
        int e0 = t * 64 + g * 16;
        const float* sx = x + ((size_t)row << 8) + e0;
        float4 v0 = *(const float4*)sx;
        float4 v1 = *(const float4*)(sx + 4);
        float4 v2 = *(const float4*)(sx + 8);
        float4 v3 = *(const float4*)(sx + 12);
        u32x4 o = {pk4(v0.x, v0.y, v0.z, v0.w), pk4(v1.x, v1.y, v1.z, v1.w),
                   pk4(v2.x, v2.y, v2.z, v2.w), pk4(v3.x, v3.y, v3.z, v3.w)};
        *(u32x4*)&Bs[rc][gi * 16] = o;
      }
      __syncthreads();
      compute(rc, t);
      if (++rc == 3) rc = 0;
    }
    __syncthreads();
  }

  // ---- epilogue: subtract C, square, reduce ----
  // z(d,n): d = ws*32 + fi*64 + (q&3)+8*(q>>2)+4*h ; n = wm*64 + nf*32 + l31
  float s0 = 0.f, s1 = 0.f;
#pragma unroll
  for (int fi = 0; fi < 4; ++fi)
#pragma unroll
    for (int qg = 0; qg < 4; ++qg) {
      f32x4 cv = *(const f32x4*)&C_lds[ws * 32 + fi * 64 + qg * 8 + 4 * h];
#pragma unroll
      for (int qi = 0; qi < 4; ++qi) {
        int q = qg * 4 + qi;
        float z0 = acc[fi][0][q] - cv[qi];
        float z1 = acc[fi][1][q] - cv[qi];
        s0 += z0 * z0;
        s1 += z1 * z1;
      }
    }
  s0 += __shfl_xor(s0, 32, 64);   // combine h halves (other 16 d-rows)
  s1 += __shfl_xor(s1, 32, 64);
  if (lane < 32) {
    spart[wm * 64 + l31][ws]      = s0;
    spart[wm * 64 + 32 + l31][ws] = s1;
  }
  __syncthreads();
  if (tid < 256) {
    // parity partials -> 2 planes; proven lse sums both.
    Sp[(size_t)k * NTOT + rb * 256 + tid]              = spart[tid][0];
    Sp[((size_t)(KC + k)) * NTOT + rb * 256 + tid]     = spart[tid][1];
  }
}

// ---------------------------------------------------------------------------
// Per-row logsumexp over K (combining 2-plane partials), mean(|logC+lse|).
// (verbatim round-0)
// ---------------------------------------------------------------------------
__global__ void gmm_lse(const float* __restrict__ Sp,
                        const float* __restrict__ ck,
                        float* __restrict__ out) {
  int n = blockIdx.x * 256 + threadIdx.x;
  float m = -1e30f, s = 0.f;
#pragma unroll 4
  for (int kk = 0; kk < KC; ++kk) {
    float sv = Sp[(size_t)kk * NTOT + n] + Sp[(size_t)(KC + kk) * NTOT + n];
    float v = ck[kk] - 0.5f * sv;
    float nm = fmaxf(m, v);
    s = s * expf(m - nm) + expf(v - nm);
    m = nm;
  }
  float lse = m + logf(s);
  const float logC = -(DN * 0.5f) * 1.8378770664093453f;  // -(D/2) log(2*pi)
  float val = fabsf(logC + lse) * (1.0f / (float)NTOT);
  int lane = threadIdx.x & 63;
  int wid  = threadIdx.x >> 6;
#pragma unroll
  for (int off = 32; off > 0; off >>= 1) val += __shfl_down(val, off, 64);
  __shared__ float wsum[4];
  if (lane == 0) wsum[wid] = val;
  __syncthreads();
  if (threadIdx.x == 0)
    atomicAdd(out, wsum[0] + wsum[1] + wsum[2] + wsum[3]);
}

// ---------------------------------------------------------------------------
extern "C" void kernel_launch(void* const* d_in, const int* in_sizes, int n_in,
                              void* d_out, int out_size, void* d_ws, size_t ws_size,
                              hipStream_t stream) {
  const float* x     = (const float*)d_in[0];
  const float* means = (const float*)d_in[1];
  const float* diag  = (const float*)d_in[2];
  const float* tri   = (const float*)d_in[3];
  const float* weigh = (const float*)d_in[4];
  float* out = (float*)d_out;

  char* ws = (char*)d_ws;
  size_t off_ck = 0;                                    // 1 KB
  size_t off_C  = 1024;                                 // 128 KB
  size_t off_Sp = off_C + (size_t)KC * DN * 4;          // 8 MB (2 planes)
  size_t off_Xp = off_Sp + (size_t)2 * KC * NTOT * 4;   // 2 MB (fp8)
  size_t off_Mp = off_Xp + (size_t)NTOT * DN;           // 8 MB (fp8)
  size_t need   = off_Mp + (size_t)KC * DN * DN;        // ~18.6 MB
  int useP = (ws_size >= need) ? 1 : 0;

  float* ck = (float*)(ws + off_ck);
  float* C  = (float*)(ws + off_C);
  float* Sp = (float*)(ws + off_Sp);
  unsigned char* Xp = (unsigned char*)(ws + off_Xp);
  unsigned char* Mp = (unsigned char*)(ws + off_Mp);

  hipMemsetAsync(d_out, 0, sizeof(float), stream);
  gmm_const<<<KC, 64, 0, stream>>>(diag, weigh, ck);
  gmm_cvec<<<KC * 4, 256, 0, stream>>>(tri, diag, means, C);
  if (useP) {
    gmm_packB<<<(KC * 4 * 2 * 512) / 256, 256, 0, stream>>>(tri, diag, Mp);
    gmm_packA<<<(32 * 4 * 1024) / 256, 256, 0, stream>>>(x, Xp);
    gmm_gemm<1><<<4096, 512, 0, stream>>>(x, tri, diag, Xp, Mp, C, Sp);
  } else {
    gmm_gemm<0><<<4096, 512, 0, stream>>>(x, tri, diag, Xp, Mp, C, Sp);
  }
  gmm_lse<<<NTOT / 256, 256, 0, stream>>>(Sp, ck, out);
}